// Round 1
// baseline (270.683 us; speedup 1.0000x reference)
//
#include <hip/hip_runtime.h>
#include <cstddef>

// Shapes: BS=16, N=1024, HID=64, D=128, F=128, C=256, NM=4, PREK=4
constexpr float PHASE_SCALE = (float)(3.141592653589793 / ((12.0 + 2.0) / 64.0));

typedef __bf16 bf16;
typedef __bf16 bf16x4 __attribute__((ext_vector_type(4)));
typedef __bf16 bf16x8 __attribute__((ext_vector_type(8)));
typedef float floatx4 __attribute__((ext_vector_type(4)));

#define GLOAD_LDS16(gp, lp) __builtin_amdgcn_global_load_lds( \
    (const __attribute__((address_space(1))) void*)(gp),      \
    (__attribute__((address_space(3))) void*)(lp), 16, 0, 0)

// ============ fused prep — 2048 blocks, sections interleaved per 8-block group ============
// group parity (bid>>3)&1 == 0 -> x0-build (1024 blocks)
//                          == 1 -> att partials (512) then weight transposes (512)
// ALL blocks additionally stream 4 units of S fp32->bf16 (grid-strided).
__global__ __launch_bounds__(256) void prep_kernel(
    const float4* __restrict__ S, bf16* __restrict__ Sbf,
    const float* __restrict__ R,
    const float* __restrict__ gcw, const float* __restrict__ W,
    bf16* __restrict__ gtAll, bf16* __restrict__ WT,
    const float* __restrict__ inp, const float* __restrict__ hs,
    bf16* __restrict__ xRow, bf16* __restrict__ xT0,
    const float* __restrict__ attw, float* __restrict__ part)
{
    __shared__ bf16 tile[64][65];
    __shared__ float red[256];
    const int bid = blockIdx.x;
    const int tid = threadIdx.x;

    // linear index within this parity class: groups of 8 keep bid%8 XCD spread
    const int lin = ((bid >> 4) << 3) | (bid & 7);      // [0,1024)

    if (((bid >> 3) & 1) == 0) {
        // ---- x0 build: one 64n x 64c quarter-tile; source is block-uniform ----
        int b = lin >> 6, by = (lin >> 2) & 15, bx = lin & 3;
        int n0 = by * 64, c0 = bx * 64;
        // c in [0,64): inp[..][c] ; [64,128): preH[c-64] ; [128,192): inp[64+cl] ; [192,256): preH[64+cl]
        const float* base = (bx & 1) ? (hs + (((size_t)b * 4 + 3) * 1024) * 128)
                                     : (inp + ((size_t)b * 1024) * 128);
        int soff = (bx >> 1) * 64;
        #pragma unroll
        for (int it = 0; it < 2; ++it) {
            int unit = it * 256 + tid;                  // 512 units = 64 rows x 8 segs
            int nl = unit >> 3, cs = unit & 7;
            const float* src = base + (size_t)(n0 + nl) * 128 + soff + cs * 8;
            float4 a0 = *(const float4*)src;
            float4 a1 = *(const float4*)(src + 4);
            bf16x8 o;
            o[0] = (bf16)a0.x; o[1] = (bf16)a0.y; o[2] = (bf16)a0.z; o[3] = (bf16)a0.w;
            o[4] = (bf16)a1.x; o[5] = (bf16)a1.y; o[6] = (bf16)a1.z; o[7] = (bf16)a1.w;
            *(bf16x8*)(xRow + ((size_t)b * 1024 + n0 + nl) * 256 + c0 + cs * 8) = o;
            #pragma unroll
            for (int e = 0; e < 8; ++e) tile[nl][cs * 8 + e] = o[e];
        }
        __syncthreads();
        #pragma unroll
        for (int it = 0; it < 4; ++it) {
            int unit = it * 256 + tid;                  // 1024 units = 64 cols x 16 n-groups
            int ng = unit & 15, cc = unit >> 4;
            bf16x4 v;
            #pragma unroll
            for (int r = 0; r < 4; ++r) v[r] = tile[ng * 4 + r][cc];
            *(bf16x4*)(xT0 + ((size_t)b * 256 + c0 + cc) * 1024 + n0 + ng * 4) = v;
        }
    } else if (lin < 512) {
        // ---- att partials (identical math to previous version) ----
        int bk = lin & 63;                              // b*4+k
        int k = bk & 3;
        int chunk = lin >> 6;                           // 0..7
        const float* hbase = hs + (size_t)bk * 131072;
        float acc = 0.f;
        for (int idx = tid; idx < 2048; idx += 256) {   // 8 iters, float4
            int h4 = (idx & 15) * 4;
            int n = chunk * 128 + (idx >> 4);
            float4 rr  = *(const float4*)(R + (size_t)k * 65536 + n * 64 + h4);
            float4 re  = *(const float4*)(hbase + (size_t)n * 128 + h4);
            float4 im  = *(const float4*)(hbase + (size_t)n * 128 + 64 + h4);
            float4 wre = *(const float4*)(attw + (size_t)n * 128 + h4);
            float4 wim = *(const float4*)(attw + (size_t)n * 128 + 64 + h4);
            float sv, cv;
            __sincosf(rr.x * PHASE_SCALE, &sv, &cv);
            acc += (cv * re.x - sv * im.x) * wre.x + (sv * re.x + cv * im.x) * wim.x;
            __sincosf(rr.y * PHASE_SCALE, &sv, &cv);
            acc += (cv * re.y - sv * im.y) * wre.y + (sv * re.y + cv * im.y) * wim.y;
            __sincosf(rr.z * PHASE_SCALE, &sv, &cv);
            acc += (cv * re.z - sv * im.z) * wre.z + (sv * re.z + cv * im.z) * wim.z;
            __sincosf(rr.w * PHASE_SCALE, &sv, &cv);
            acc += (cv * re.w - sv * im.w) * wre.w + (sv * re.w + cv * im.w) * wim.w;
        }
        red[tid] = acc;
        __syncthreads();
        for (int s2 = 128; s2 > 0; s2 >>= 1) {
            if (tid < s2) red[tid] += red[tid + s2];
            __syncthreads();
        }
        if (tid == 0) part[bk * 8 + chunk] = red[0];
    } else {
        // ---- weight transposes, grid-strided over 147456 elems (512 blocks) ----
        int wid = lin - 512;
        for (int wi = wid * 256 + tid; wi < 147456; wi += 131072) {
            if (wi < 131072) {
                int m = wi >> 15;
                int rem = wi & 32767;
                int d = rem >> 8;
                int c = rem & 255;
                gtAll[wi] = (bf16)gcw[(size_t)d * 1024 + c * 4 + m];  // gtAll[m][d][c]
            } else {
                int r2 = wi - 131072;
                int n = r2 >> 7, kx = r2 & 127;
                WT[r2] = (bf16)W[(size_t)kx * 128 + n];               // WT[n][k]
            }
        }
    }

    // ---- S fp32->bf16: every block streams 4 units (2048*4 = 8192 units total) ----
    #pragma unroll
    for (int i = 0; i < 4; ++i) {
        size_t gi = ((size_t)(bid * 4 + i)) * 256 + tid;   // [0, 2097152)
        const float4* Sp = S + gi * 2;
        float4 v0 = Sp[0];
        float4 v1 = Sp[1];
        bf16x8 o;
        o[0] = (bf16)v0.x; o[1] = (bf16)v0.y; o[2] = (bf16)v0.z; o[3] = (bf16)v0.w;
        o[4] = (bf16)v1.x; o[5] = (bf16)v1.y; o[6] = (bf16)v1.z; o[7] = (bf16)v1.w;
        *(bf16x8*)(Sbf + gi * 8) = o;
    }
}

// ============ Chebyshev MFMA + fused per-hop gco (non-atomic: block owns full rows) ===========
// Block = 64 rows x 256 cols (full C) of one batch. 256 blocks, 8 waves (512 thr).
// LDS double-buffered; global_load_lds staged; one barrier per K-step.
// Epilogue: xnext -> xTout (bf16x4) ; LDS-transpose -> xnext @ gt_h^T (+ x0 @ gt0^T on hop1)
// accumulated into gcoF (plain store hop1, += hops 2/3).
__global__ __launch_bounds__(512) void cheb_mfma_kernel(
    const bf16* __restrict__ S, const bf16* __restrict__ xT,
    const bf16* __restrict__ xTprev, bf16* __restrict__ outT,
    const bf16* __restrict__ xRow0, const bf16* __restrict__ gtA,
    const bf16* __restrict__ gt0, float* __restrict__ gcoF,
    float alpha, int accumulate)
{
    __shared__ char smem[81920];                  // 2 x (A 8KB + B 32KB)
    const int f = blockIdx.x;
    const int b = (f & 7) + 8 * ((f >> 3) & 1);   // batch -> XCD f%8
    const int n0 = (f >> 4) * 64;
    const int tid = threadIdx.x;
    const int wave = tid >> 6, lane = tid & 63;
    const int wr = (wave & 3) * 16;               // 16-row group
    const int wc = (wave >> 2) * 128;             // 128-col half
    const int l15 = lane & 15, quad = lane >> 4;
    const int lrow = lane >> 3;                   // staging: 8 rows x 8 segs
    const int segsw = (lane & 7) ^ lrow;

    const bf16* Sb = S + (size_t)b * 1048576;
    const bf16* xb = xT + (size_t)b * 262144;

    auto stage = [&](int p, int k0) {
        bf16* dA = (bf16*)(smem + p * 40960);
        bf16* dB = dA + 4096;                     // 8192 B after A
        // A: wave stages rows [wave*8, wave*8+8)
        {
            const bf16* gp = Sb + (size_t)(n0 + wave * 8 + lrow) * 1024 + k0 + segsw * 8;
            GLOAD_LDS16(gp, dA + wave * 8 * 64);
        }
        // B: wave stages cols [wave*32, wave*32+32)
        #pragma unroll
        for (int v = 0; v < 4; ++v) {
            int cq = wave * 32 + v * 8;
            const bf16* gp = xb + (size_t)(cq + lrow) * 1024 + k0 + segsw * 8;
            GLOAD_LDS16(gp, dB + cq * 64);
        }
    };

    floatx4 acc[8] = {};
    stage(0, 0);
    int p = 0;
    for (int k0 = 0; k0 < 1024; k0 += 64) {
        __syncthreads();                          // drains DMA of buf p; guards reuse
        if (k0 + 64 < 1024) stage(p ^ 1, k0 + 64);
        const bf16* lA = (const bf16*)(smem + p * 40960);
        const bf16* lB = lA + 4096;
        #pragma unroll
        for (int ks = 0; ks < 2; ++ks) {
            int row = wr + l15;
            int aslot = (ks * 4 + quad) ^ (row & 7);
            bf16x8 af = *(const bf16x8*)(lA + row * 64 + aslot * 8);
            #pragma unroll
            for (int j = 0; j < 8; ++j) {
                int col = wc + j * 16 + l15;
                int bslot = (ks * 4 + quad) ^ (col & 7);
                bf16x8 bfr = *(const bf16x8*)(lB + col * 64 + bslot * 8);
                acc[j] = __builtin_amdgcn_mfma_f32_16x16x32_bf16(af, bfr, acc[j], 0, 0, 0);
            }
        }
        p ^= 1;
    }

    // ---- epilogue: xnext = alpha*acc - xprev ----
    const bf16* pT = xTprev ? xTprev + (size_t)b * 262144 : nullptr;
    bf16* oT = outT ? outT + (size_t)b * 262144 : nullptr;
    bf16x4 xo[8];
    #pragma unroll
    for (int j = 0; j < 8; ++j) {
        int col = wc + j * 16 + l15;
        float v[4];
        #pragma unroll
        for (int r = 0; r < 4; ++r) v[r] = alpha * acc[j][r];
        if (pT) {
            bf16x4 pp = *(const bf16x4*)(pT + (size_t)col * 1024 + n0 + wr + quad * 4);
            #pragma unroll
            for (int r = 0; r < 4; ++r) v[r] -= (float)pp[r];
        }
        #pragma unroll
        for (int r = 0; r < 4; ++r) xo[j][r] = (bf16)v[r];
        if (oT) *(bf16x4*)(oT + (size_t)col * 1024 + n0 + wr + quad * 4) = xo[j];
    }

    // ---- LDS transpose of xnext tile (64 x 256, pad to 264) ----
    __syncthreads();                              // all waves done reading dbuf
    bf16* ldsX = (bf16*)smem;
    #pragma unroll
    for (int j = 0; j < 8; ++j) {
        int col = wc + j * 16 + l15;
        #pragma unroll
        for (int r = 0; r < 4; ++r)
            ldsX[(wr + quad * 4 + r) * 264 + col] = xo[j][r];
    }
    __syncthreads();

    // ---- gco: (xnext tile) @ gt_h^T (+ x0 @ gt0^T on hop1) -> gcoF rows ----
    const int dbase = (wave >> 2) * 64;           // this wave's 64 d-cols
    floatx4 a2[4] = {};
    for (int k2 = 0; k2 < 256; k2 += 32) {
        bf16x8 af = *(const bf16x8*)(ldsX + (wr + l15) * 264 + k2 + quad * 8);
        #pragma unroll
        for (int j = 0; j < 4; ++j) {
            int dcol = dbase + j * 16 + l15;
            bf16x8 bfr = *(const bf16x8*)(gtA + (size_t)dcol * 256 + k2 + quad * 8);
            a2[j] = __builtin_amdgcn_mfma_f32_16x16x32_bf16(af, bfr, a2[j], 0, 0, 0);
        }
    }
    if (xRow0) {                                  // hop1: add x0 @ gt0^T
        for (int k2 = 0; k2 < 256; k2 += 32) {
            bf16x8 af = *(const bf16x8*)(xRow0 + ((size_t)b * 1024 + n0 + wr + l15) * 256 + k2 + quad * 8);
            #pragma unroll
            for (int j = 0; j < 4; ++j) {
                int dcol = dbase + j * 16 + l15;
                bf16x8 bfr = *(const bf16x8*)(gt0 + (size_t)dcol * 256 + k2 + quad * 8);
                a2[j] = __builtin_amdgcn_mfma_f32_16x16x32_bf16(af, bfr, a2[j], 0, 0, 0);
            }
        }
    }
    #pragma unroll
    for (int j = 0; j < 4; ++j) {
        int dcol = dbase + j * 16 + l15;
        #pragma unroll
        for (int r = 0; r < 4; ++r) {
            size_t idx = ((size_t)b * 1024 + n0 + wr + quad * 4 + r) * 128 + dcol;
            if (accumulate) gcoF[idx] += a2[j][r];
            else            gcoF[idx]  = a2[j][r];
        }
    }
}

// ============ final: out = leaky(gcoF+gcb) @ WT^T + b + att ; + newh copy + newh[3] ============
// 256 blocks x 64 rows; no LDS (A-frags built in-register from gcoF).
__global__ __launch_bounds__(256) void final_kernel(
    const float* __restrict__ gcoF, const float* __restrict__ gcb,
    const bf16* __restrict__ WT, const float* __restrict__ bvec,
    const float* __restrict__ hs, const float* __restrict__ R,
    const float* __restrict__ part, const float* __restrict__ attb,
    float* __restrict__ out, float* __restrict__ newh)
{
    const int m0 = blockIdx.x * 64;
    const int b = m0 >> 10, n0 = m0 & 1023;
    const int tid = threadIdx.x;
    const int wave = tid >> 6, lane = tid & 63;
    const int l15 = lane & 15, quad = lane >> 4;

    // ---- phase A: leaky(gcoF+gcb) @ W ----
    const int arow = m0 + wave * 16 + l15;
    floatx4 acc[8] = {};
    #pragma unroll
    for (int k0 = 0; k0 < 128; k0 += 32) {
        int kk = k0 + quad * 8;
        float4 p0 = *(const float4*)(gcoF + (size_t)arow * 128 + kk);
        float4 p1 = *(const float4*)(gcoF + (size_t)arow * 128 + kk + 4);
        float4 g0 = *(const float4*)(gcb + kk);
        float4 g1 = *(const float4*)(gcb + kk + 4);
        float vv[8] = {p0.x + g0.x, p0.y + g0.y, p0.z + g0.z, p0.w + g0.w,
                       p1.x + g1.x, p1.y + g1.y, p1.z + g1.z, p1.w + g1.w};
        bf16x8 af;
        #pragma unroll
        for (int e = 0; e < 8; ++e) {
            float v = vv[e];
            af[e] = (bf16)(v >= 0.f ? v : 0.01f * v);
        }
        #pragma unroll
        for (int j = 0; j < 8; ++j) {
            bf16x8 bfr = *(const bf16x8*)(WT + (size_t)(j * 16 + l15) * 128 + kk);
            acc[j] = __builtin_amdgcn_mfma_f32_16x16x32_bf16(af, bfr, acc[j], 0, 0, 0);
        }
    }

    // ---- softmax weights wa[b][k] from partials ----
    float sa[4], mx = -1e30f;
    #pragma unroll
    for (int k = 0; k < 4; ++k) {
        float s = attb[0];
        #pragma unroll
        for (int c = 0; c < 8; ++c) s += part[(b * 4 + k) * 8 + c];
        sa[k] = s;
        mx = fmaxf(mx, s);
    }
    float den = 0.f;
    #pragma unroll
    for (int k = 0; k < 4; ++k) { sa[k] = __expf(sa[k] - mx); den += sa[k]; }
    float inv = 1.f / den;
    #pragma unroll
    for (int k = 0; k < 4; ++k) sa[k] *= inv;

    // ---- phase B: att + newh copy + stores (jj pairs d and d+64) ----
    #pragma unroll
    for (int jj = 0; jj < 4; ++jj) {
        int hcol = jj * 16 + l15;                 // h in [0,64)
        #pragma unroll
        for (int r = 0; r < 4; ++r) {
            int n = n0 + wave * 16 + quad * 4 + r;
            float attRe = 0.f, attIm = 0.f;
            #pragma unroll
            for (int k = 0; k < 4; ++k) {
                const float* hb = hs + (((size_t)(b * 4 + k) * 1024 + n) * 128);
                float re = hb[hcol], im = hb[64 + hcol];
                float s, c;
                __sincosf(R[(size_t)k * 65536 + n * 64 + hcol] * PHASE_SCALE, &s, &c);
                attRe += sa[k] * (c * re - s * im);
                attIm += sa[k] * (s * re + c * im);
                if (k >= 1) {
                    size_t nb = (size_t)b * 524288 + (size_t)(k - 1) * 131072 + (size_t)n * 128;
                    newh[nb + hcol] = re;
                    newh[nb + 64 + hcol] = im;
                }
            }
            size_t ob = (size_t)(m0 + wave * 16 + quad * 4 + r) * 128;
            float oRe = acc[jj][r]     + bvec[(size_t)n * 128 + hcol]      + attRe;
            float oIm = acc[jj + 4][r] + bvec[(size_t)n * 128 + 64 + hcol] + attIm;
            out[ob + hcol] = oRe;
            out[ob + 64 + hcol] = oIm;
            size_t nb3 = (size_t)b * 524288 + 393216 + (size_t)n * 128;
            newh[nb3 + hcol] = oRe;
            newh[nb3 + 64 + hcol] = oIm;
        }
    }
}

extern "C" void kernel_launch(void* const* d_in, const int* in_sizes, int n_in,
                              void* d_out, int out_size, void* d_ws, size_t ws_size,
                              hipStream_t stream) {
    const float* inp  = (const float*)d_in[0];
    const float* sup  = (const float*)d_in[1];
    const float* hs   = (const float*)d_in[2];
    const float* W    = (const float*)d_in[3];
    const float* bvec = (const float*)d_in[4];
    const float* R    = (const float*)d_in[5];
    const float* gcw  = (const float*)d_in[6];
    const float* gcb  = (const float*)d_in[7];
    // d_in[8], d_in[9] (ev_att_w/b) dead: softmax over size-1 axis == 1
    const float* attw = (const float*)d_in[10];
    const float* attb = (const float*)d_in[11];

    float* out  = (float*)d_out;                    // (16,1024,128)
    float* newh = out + 2097152;                    // (16,4,1024,128)
    bf16*  Sbf  = (bf16*)newh;                      // S bf16 here until final_kernel

    char* w = (char*)d_ws;
    bf16*  xT0   = (bf16*)(w);                      // 8 MB  [16][256][1024]
    bf16*  xT1   = (bf16*)(w + 8388608);            // 8 MB
    bf16*  xT2   = (bf16*)(w + 16777216);           // 8 MB
    bf16*  xRow  = (bf16*)(w + 25165824);           // 8 MB  [16384][256]
    float* gcoF  = (float*)(w + 33554432);          // 8 MB  [16384][128]
    bf16*  gtAll = (bf16*)(w + 41943040);           // 256 KB [4][128][256]
    bf16*  WT    = (bf16*)(w + 42205184);           // 32 KB  [128][128]
    float* part  = (float*)(w + 42237952);          // 2 KB
    // total ~40.3 MB

    prep_kernel<<<2048, 256, 0, stream>>>((const float4*)sup, Sbf, R, gcw, W,
                                          gtAll, WT, inp, hs, xRow, xT0, attw, part);

    // hop1: x1 = S@x0 ; gcoF = x0@g0 + x1@g1
    cheb_mfma_kernel<<<256, 512, 0, stream>>>(Sbf, xT0, nullptr, xT1,
                                              xRow, gtAll + 32768, gtAll, gcoF, 1.0f, 0);
    // hop2: x2 = 2S@x1 - x0 ; gcoF += x2@g2
    cheb_mfma_kernel<<<256, 512, 0, stream>>>(Sbf, xT1, xT0, xT2,
                                              nullptr, gtAll + 2 * 32768, nullptr, gcoF, 2.0f, 1);
    // hop3: x3 = 2S@x2 - x1 ; gcoF += x3@g3 (no xT output)
    cheb_mfma_kernel<<<256, 512, 0, stream>>>(Sbf, xT2, xT1, nullptr,
                                              nullptr, gtAll + 3 * 32768, nullptr, gcoF, 2.0f, 1);

    // Sbf (in newh region) dead now -> final writes out + all of newh
    final_kernel<<<256, 256, 0, stream>>>(gcoF, gcb, WT, bvec, hs, R, part, attb, out, newh);
}

// Round 2
// 268.779 us; speedup vs baseline: 1.0071x; 1.0071x over previous
//
#include <hip/hip_runtime.h>
#include <cstddef>

// Shapes: BS=16, N=1024, HID=64, D=128, F=128, C=256, NM=4, PREK=4
constexpr float PHASE_SCALE = (float)(3.141592653589793 / ((12.0 + 2.0) / 64.0));

typedef __bf16 bf16;
typedef __bf16 bf16x4 __attribute__((ext_vector_type(4)));
typedef __bf16 bf16x8 __attribute__((ext_vector_type(8)));
typedef float floatx4 __attribute__((ext_vector_type(4)));

#define GLOAD_LDS16(gp, lp) __builtin_amdgcn_global_load_lds( \
    (const __attribute__((address_space(1))) void*)(gp),      \
    (__attribute__((address_space(3))) void*)(lp), 16, 0, 0)

// ============ fused prep — sequential sections, longest-latency first ============
// [0,512): att partials (sincos-heavy, longest) ; [512,1536): x0 build (vectorized) ;
// [1536,2112): weight transposes ; [2112,6208): S fp32->bf16 (2 units/thread)
__global__ __launch_bounds__(256) void prep_kernel(
    const float4* __restrict__ S, bf16* __restrict__ Sbf,
    const float* __restrict__ R,
    const float* __restrict__ gcw, const float* __restrict__ W,
    bf16* __restrict__ gtAll, bf16* __restrict__ WT,
    const float* __restrict__ inp, const float* __restrict__ hs,
    bf16* __restrict__ xRow, bf16* __restrict__ xT0,
    const float* __restrict__ attw, float* __restrict__ part)
{
    __shared__ bf16 tile[64][65];
    __shared__ float red[256];
    const int bid = blockIdx.x;
    const int tid = threadIdx.x;

    if (bid < 512) {
        // ---- att partials ----
        int bk = bid & 63;                              // b*4+k
        int k = bk & 3;
        int chunk = bid >> 6;                           // 0..7
        const float* hbase = hs + (size_t)bk * 131072;
        float acc = 0.f;
        for (int idx = tid; idx < 2048; idx += 256) {   // 8 iters, float4
            int h4 = (idx & 15) * 4;
            int n = chunk * 128 + (idx >> 4);
            float4 rr  = *(const float4*)(R + (size_t)k * 65536 + n * 64 + h4);
            float4 re  = *(const float4*)(hbase + (size_t)n * 128 + h4);
            float4 im  = *(const float4*)(hbase + (size_t)n * 128 + 64 + h4);
            float4 wre = *(const float4*)(attw + (size_t)n * 128 + h4);
            float4 wim = *(const float4*)(attw + (size_t)n * 128 + 64 + h4);
            float sv, cv;
            __sincosf(rr.x * PHASE_SCALE, &sv, &cv);
            acc += (cv * re.x - sv * im.x) * wre.x + (sv * re.x + cv * im.x) * wim.x;
            __sincosf(rr.y * PHASE_SCALE, &sv, &cv);
            acc += (cv * re.y - sv * im.y) * wre.y + (sv * re.y + cv * im.y) * wim.y;
            __sincosf(rr.z * PHASE_SCALE, &sv, &cv);
            acc += (cv * re.z - sv * im.z) * wre.z + (sv * re.z + cv * im.z) * wim.z;
            __sincosf(rr.w * PHASE_SCALE, &sv, &cv);
            acc += (cv * re.w - sv * im.w) * wre.w + (sv * re.w + cv * im.w) * wim.w;
        }
        red[tid] = acc;
        __syncthreads();
        for (int s2 = 128; s2 > 0; s2 >>= 1) {
            if (tid < s2) red[tid] += red[tid + s2];
            __syncthreads();
        }
        if (tid == 0) part[bk * 8 + chunk] = red[0];
    } else if (bid < 1536) {
        // ---- x0 build: one 64n x 64c quarter-tile; source is block-uniform ----
        int lin = bid - 512;
        int b = lin >> 6, by = (lin >> 2) & 15, bx = lin & 3;
        int n0 = by * 64, c0 = bx * 64;
        // c in [0,64): inp[c] ; [64,128): preH[c-64] ; [128,192): inp[64+cl] ; [192,256): preH[64+cl]
        const float* base = (bx & 1) ? (hs + (((size_t)b * 4 + 3) * 1024) * 128)
                                     : (inp + ((size_t)b * 1024) * 128);
        int soff = (bx >> 1) * 64;
        #pragma unroll
        for (int it = 0; it < 2; ++it) {
            int unit = it * 256 + tid;                  // 512 units = 64 rows x 8 segs
            int nl = unit >> 3, cs = unit & 7;
            const float* src = base + (size_t)(n0 + nl) * 128 + soff + cs * 8;
            float4 a0 = *(const float4*)src;
            float4 a1 = *(const float4*)(src + 4);
            bf16x8 o;
            o[0] = (bf16)a0.x; o[1] = (bf16)a0.y; o[2] = (bf16)a0.z; o[3] = (bf16)a0.w;
            o[4] = (bf16)a1.x; o[5] = (bf16)a1.y; o[6] = (bf16)a1.z; o[7] = (bf16)a1.w;
            *(bf16x8*)(xRow + ((size_t)b * 1024 + n0 + nl) * 256 + c0 + cs * 8) = o;
            #pragma unroll
            for (int e = 0; e < 8; ++e) tile[nl][cs * 8 + e] = o[e];
        }
        __syncthreads();
        #pragma unroll
        for (int it = 0; it < 4; ++it) {
            int unit = it * 256 + tid;                  // 1024 units = 64 cols x 16 n-groups
            int ng = unit & 15, cc = unit >> 4;
            bf16x4 v;
            #pragma unroll
            for (int r = 0; r < 4; ++r) v[r] = tile[ng * 4 + r][cc];
            *(bf16x4*)(xT0 + ((size_t)b * 256 + c0 + cc) * 1024 + n0 + ng * 4) = v;
        }
    } else if (bid < 2112) {
        // ---- weight transposes ----
        int gi = (bid - 1536) * 256 + tid;              // 147,456
        if (gi < 131072) {
            int m = gi >> 15;
            int rem = gi & 32767;
            int d = rem >> 8;
            int c = rem & 255;
            gtAll[gi] = (bf16)gcw[(size_t)d * 1024 + c * 4 + m];  // gtAll[m][d][c]
        } else {
            int r = gi - 131072;
            int n = r >> 7, k = r & 127;
            WT[r] = (bf16)W[(size_t)k * 128 + n];                 // WT[n][k]
        }
    } else {
        // ---- S fp32->bf16: 2 units/thread (4 float4 loads in flight) ----
        size_t u = (size_t)(bid - 2112) * 512;          // 4096 blocks x 512 units
        #pragma unroll
        for (int i = 0; i < 2; ++i) {
            size_t gi = u + i * 256 + tid;
            const float4* Sp = S + gi * 2;
            float4 v0 = Sp[0];
            float4 v1 = Sp[1];
            bf16x8 o;
            o[0] = (bf16)v0.x; o[1] = (bf16)v0.y; o[2] = (bf16)v0.z; o[3] = (bf16)v0.w;
            o[4] = (bf16)v1.x; o[5] = (bf16)v1.y; o[6] = (bf16)v1.z; o[7] = (bf16)v1.w;
            *(bf16x8*)(Sbf + gi * 8) = o;
        }
    }
}

// ============ Chebyshev MFMA + fused per-hop gco (non-atomic: block owns full rows) ===========
// Block = 64 rows x 256 cols (full C) of one batch. 256 blocks, 8 waves (512 thr).
// LDS double-buffered; global_load_lds staged; one barrier per K-step.
// Epilogue: xnext -> xTout (bf16x4) ; LDS-transpose -> xnext @ gt_h^T (+ x0 @ gt0^T on hop1)
// accumulated into gcoF (plain store hop1, += hops 2/3).
__global__ __launch_bounds__(512) void cheb_mfma_kernel(
    const bf16* __restrict__ S, const bf16* __restrict__ xT,
    const bf16* __restrict__ xTprev, bf16* __restrict__ outT,
    const bf16* __restrict__ xRow0, const bf16* __restrict__ gtA,
    const bf16* __restrict__ gt0, float* __restrict__ gcoF,
    float alpha, int accumulate)
{
    __shared__ char smem[81920];                  // 2 x (A 8KB + B 32KB)
    const int f = blockIdx.x;
    const int b = (f & 7) + 8 * ((f >> 3) & 1);   // batch -> XCD f%8
    const int n0 = (f >> 4) * 64;
    const int tid = threadIdx.x;
    const int wave = tid >> 6, lane = tid & 63;
    const int wr = (wave & 3) * 16;               // 16-row group
    const int wc = (wave >> 2) * 128;             // 128-col half
    const int l15 = lane & 15, quad = lane >> 4;
    const int lrow = lane >> 3;                   // staging: 8 rows x 8 segs
    const int segsw = (lane & 7) ^ lrow;

    const bf16* Sb = S + (size_t)b * 1048576;
    const bf16* xb = xT + (size_t)b * 262144;

    auto stage = [&](int p, int k0) {
        bf16* dA = (bf16*)(smem + p * 40960);
        bf16* dB = dA + 4096;                     // 8192 B after A
        // A: wave stages rows [wave*8, wave*8+8)
        {
            const bf16* gp = Sb + (size_t)(n0 + wave * 8 + lrow) * 1024 + k0 + segsw * 8;
            GLOAD_LDS16(gp, dA + wave * 8 * 64);
        }
        // B: wave stages cols [wave*32, wave*32+32)
        #pragma unroll
        for (int v = 0; v < 4; ++v) {
            int cq = wave * 32 + v * 8;
            const bf16* gp = xb + (size_t)(cq + lrow) * 1024 + k0 + segsw * 8;
            GLOAD_LDS16(gp, dB + cq * 64);
        }
    };

    floatx4 acc[8] = {};
    stage(0, 0);
    int p = 0;
    for (int k0 = 0; k0 < 1024; k0 += 64) {
        __syncthreads();                          // drains DMA of buf p; guards reuse
        if (k0 + 64 < 1024) stage(p ^ 1, k0 + 64);
        const bf16* lA = (const bf16*)(smem + p * 40960);
        const bf16* lB = lA + 4096;
        #pragma unroll
        for (int ks = 0; ks < 2; ++ks) {
            int row = wr + l15;
            int aslot = (ks * 4 + quad) ^ (row & 7);
            bf16x8 af = *(const bf16x8*)(lA + row * 64 + aslot * 8);
            #pragma unroll
            for (int j = 0; j < 8; ++j) {
                int col = wc + j * 16 + l15;
                int bslot = (ks * 4 + quad) ^ (col & 7);
                bf16x8 bfr = *(const bf16x8*)(lB + col * 64 + bslot * 8);
                acc[j] = __builtin_amdgcn_mfma_f32_16x16x32_bf16(af, bfr, acc[j], 0, 0, 0);
            }
        }
        p ^= 1;
    }

    // ---- epilogue: xnext = alpha*acc - xprev ----
    const bf16* pT = xTprev ? xTprev + (size_t)b * 262144 : nullptr;
    bf16* oT = outT ? outT + (size_t)b * 262144 : nullptr;
    bf16x4 xo[8];
    #pragma unroll
    for (int j = 0; j < 8; ++j) {
        int col = wc + j * 16 + l15;
        float v[4];
        #pragma unroll
        for (int r = 0; r < 4; ++r) v[r] = alpha * acc[j][r];
        if (pT) {
            bf16x4 pp = *(const bf16x4*)(pT + (size_t)col * 1024 + n0 + wr + quad * 4);
            #pragma unroll
            for (int r = 0; r < 4; ++r) v[r] -= (float)pp[r];
        }
        #pragma unroll
        for (int r = 0; r < 4; ++r) xo[j][r] = (bf16)v[r];
        if (oT) *(bf16x4*)(oT + (size_t)col * 1024 + n0 + wr + quad * 4) = xo[j];
    }

    // ---- LDS transpose of xnext tile (64 x 256, pad to 264) ----
    __syncthreads();                              // all waves done reading dbuf
    bf16* ldsX = (bf16*)smem;
    #pragma unroll
    for (int j = 0; j < 8; ++j) {
        int col = wc + j * 16 + l15;
        #pragma unroll
        for (int r = 0; r < 4; ++r)
            ldsX[(wr + quad * 4 + r) * 264 + col] = xo[j][r];
    }
    __syncthreads();

    // ---- gco: (xnext tile) @ gt_h^T (+ x0 @ gt0^T on hop1) -> gcoF rows ----
    const int dbase = (wave >> 2) * 64;           // this wave's 64 d-cols
    floatx4 a2[4] = {};
    for (int k2 = 0; k2 < 256; k2 += 32) {
        bf16x8 af = *(const bf16x8*)(ldsX + (wr + l15) * 264 + k2 + quad * 8);
        #pragma unroll
        for (int j = 0; j < 4; ++j) {
            int dcol = dbase + j * 16 + l15;
            bf16x8 bfr = *(const bf16x8*)(gtA + (size_t)dcol * 256 + k2 + quad * 8);
            a2[j] = __builtin_amdgcn_mfma_f32_16x16x32_bf16(af, bfr, a2[j], 0, 0, 0);
        }
    }
    if (xRow0) {                                  // hop1: add x0 @ gt0^T
        for (int k2 = 0; k2 < 256; k2 += 32) {
            bf16x8 af = *(const bf16x8*)(xRow0 + ((size_t)b * 1024 + n0 + wr + l15) * 256 + k2 + quad * 8);
            #pragma unroll
            for (int j = 0; j < 4; ++j) {
                int dcol = dbase + j * 16 + l15;
                bf16x8 bfr = *(const bf16x8*)(gt0 + (size_t)dcol * 256 + k2 + quad * 8);
                a2[j] = __builtin_amdgcn_mfma_f32_16x16x32_bf16(af, bfr, a2[j], 0, 0, 0);
            }
        }
    }
    #pragma unroll
    for (int j = 0; j < 4; ++j) {
        int dcol = dbase + j * 16 + l15;
        #pragma unroll
        for (int r = 0; r < 4; ++r) {
            size_t idx = ((size_t)b * 1024 + n0 + wr + quad * 4 + r) * 128 + dcol;
            if (accumulate) gcoF[idx] += a2[j][r];
            else            gcoF[idx]  = a2[j][r];
        }
    }
}

// ============ final: out = leaky(gcoF+gcb) @ WT^T + b + att ; + newh copy + newh[3] ============
// 256 blocks x 64 rows; no LDS (A-frags built in-register from gcoF).
__global__ __launch_bounds__(256) void final_kernel(
    const float* __restrict__ gcoF, const float* __restrict__ gcb,
    const bf16* __restrict__ WT, const float* __restrict__ bvec,
    const float* __restrict__ hs, const float* __restrict__ R,
    const float* __restrict__ part, const float* __restrict__ attb,
    float* __restrict__ out, float* __restrict__ newh)
{
    const int m0 = blockIdx.x * 64;
    const int b = m0 >> 10, n0 = m0 & 1023;
    const int tid = threadIdx.x;
    const int wave = tid >> 6, lane = tid & 63;
    const int l15 = lane & 15, quad = lane >> 4;

    // ---- phase A: leaky(gcoF+gcb) @ W ----
    const int arow = m0 + wave * 16 + l15;
    floatx4 acc[8] = {};
    #pragma unroll
    for (int k0 = 0; k0 < 128; k0 += 32) {
        int kk = k0 + quad * 8;
        float4 p0 = *(const float4*)(gcoF + (size_t)arow * 128 + kk);
        float4 p1 = *(const float4*)(gcoF + (size_t)arow * 128 + kk + 4);
        float4 g0 = *(const float4*)(gcb + kk);
        float4 g1 = *(const float4*)(gcb + kk + 4);
        float vv[8] = {p0.x + g0.x, p0.y + g0.y, p0.z + g0.z, p0.w + g0.w,
                       p1.x + g1.x, p1.y + g1.y, p1.z + g1.z, p1.w + g1.w};
        bf16x8 af;
        #pragma unroll
        for (int e = 0; e < 8; ++e) {
            float v = vv[e];
            af[e] = (bf16)(v >= 0.f ? v : 0.01f * v);
        }
        #pragma unroll
        for (int j = 0; j < 8; ++j) {
            bf16x8 bfr = *(const bf16x8*)(WT + (size_t)(j * 16 + l15) * 128 + kk);
            acc[j] = __builtin_amdgcn_mfma_f32_16x16x32_bf16(af, bfr, acc[j], 0, 0, 0);
        }
    }

    // ---- softmax weights wa[b][k] from partials ----
    float sa[4], mx = -1e30f;
    #pragma unroll
    for (int k = 0; k < 4; ++k) {
        float s = attb[0];
        #pragma unroll
        for (int c = 0; c < 8; ++c) s += part[(b * 4 + k) * 8 + c];
        sa[k] = s;
        mx = fmaxf(mx, s);
    }
    float den = 0.f;
    #pragma unroll
    for (int k = 0; k < 4; ++k) { sa[k] = __expf(sa[k] - mx); den += sa[k]; }
    float inv = 1.f / den;
    #pragma unroll
    for (int k = 0; k < 4; ++k) sa[k] *= inv;

    // ---- phase B: att + newh copy + stores (jj pairs d and d+64) ----
    #pragma unroll
    for (int jj = 0; jj < 4; ++jj) {
        int hcol = jj * 16 + l15;                 // h in [0,64)
        #pragma unroll
        for (int r = 0; r < 4; ++r) {
            int n = n0 + wave * 16 + quad * 4 + r;
            float attRe = 0.f, attIm = 0.f;
            #pragma unroll
            for (int k = 0; k < 4; ++k) {
                const float* hb = hs + (((size_t)(b * 4 + k) * 1024 + n) * 128);
                float re = hb[hcol], im = hb[64 + hcol];
                float s, c;
                __sincosf(R[(size_t)k * 65536 + n * 64 + hcol] * PHASE_SCALE, &s, &c);
                attRe += sa[k] * (c * re - s * im);
                attIm += sa[k] * (s * re + c * im);
                if (k >= 1) {
                    size_t nb = (size_t)b * 524288 + (size_t)(k - 1) * 131072 + (size_t)n * 128;
                    newh[nb + hcol] = re;
                    newh[nb + 64 + hcol] = im;
                }
            }
            size_t ob = (size_t)(m0 + wave * 16 + quad * 4 + r) * 128;
            float oRe = acc[jj][r]     + bvec[(size_t)n * 128 + hcol]      + attRe;
            float oIm = acc[jj + 4][r] + bvec[(size_t)n * 128 + 64 + hcol] + attIm;
            out[ob + hcol] = oRe;
            out[ob + 64 + hcol] = oIm;
            size_t nb3 = (size_t)b * 524288 + 393216 + (size_t)n * 128;
            newh[nb3 + hcol] = oRe;
            newh[nb3 + 64 + hcol] = oIm;
        }
    }
}

extern "C" void kernel_launch(void* const* d_in, const int* in_sizes, int n_in,
                              void* d_out, int out_size, void* d_ws, size_t ws_size,
                              hipStream_t stream) {
    const float* inp  = (const float*)d_in[0];
    const float* sup  = (const float*)d_in[1];
    const float* hs   = (const float*)d_in[2];
    const float* W    = (const float*)d_in[3];
    const float* bvec = (const float*)d_in[4];
    const float* R    = (const float*)d_in[5];
    const float* gcw  = (const float*)d_in[6];
    const float* gcb  = (const float*)d_in[7];
    // d_in[8], d_in[9] (ev_att_w/b) dead: softmax over size-1 axis == 1
    const float* attw = (const float*)d_in[10];
    const float* attb = (const float*)d_in[11];

    float* out  = (float*)d_out;                    // (16,1024,128)
    float* newh = out + 2097152;                    // (16,4,1024,128)
    bf16*  Sbf  = (bf16*)newh;                      // S bf16 here until final_kernel

    char* w = (char*)d_ws;
    bf16*  xT0   = (bf16*)(w);                      // 8 MB  [16][256][1024]
    bf16*  xT1   = (bf16*)(w + 8388608);            // 8 MB
    bf16*  xT2   = (bf16*)(w + 16777216);           // 8 MB
    bf16*  xRow  = (bf16*)(w + 25165824);           // 8 MB  [16384][256]
    float* gcoF  = (float*)(w + 33554432);          // 8 MB  [16384][128]
    bf16*  gtAll = (bf16*)(w + 41943040);           // 256 KB [4][128][256]
    bf16*  WT    = (bf16*)(w + 42205184);           // 32 KB  [128][128]
    float* part  = (float*)(w + 42237952);          // 2 KB
    // total ~40.3 MB

    prep_kernel<<<6208, 256, 0, stream>>>((const float4*)sup, Sbf, R, gcw, W,
                                          gtAll, WT, inp, hs, xRow, xT0, attw, part);

    // hop1: x1 = S@x0 ; gcoF = x0@g0 + x1@g1
    cheb_mfma_kernel<<<256, 512, 0, stream>>>(Sbf, xT0, nullptr, xT1,
                                              xRow, gtAll + 32768, gtAll, gcoF, 1.0f, 0);
    // hop2: x2 = 2S@x1 - x0 ; gcoF += x2@g2
    cheb_mfma_kernel<<<256, 512, 0, stream>>>(Sbf, xT1, xT0, xT2,
                                              nullptr, gtAll + 2 * 32768, nullptr, gcoF, 2.0f, 1);
    // hop3: x3 = 2S@x2 - x1 ; gcoF += x3@g3 (no xT output)
    cheb_mfma_kernel<<<256, 512, 0, stream>>>(Sbf, xT2, xT1, nullptr,
                                              nullptr, gtAll + 3 * 32768, nullptr, gcoF, 2.0f, 1);

    // Sbf (in newh region) dead now -> final writes out + all of newh
    final_kernel<<<256, 256, 0, stream>>>(gcoF, gcb, WT, bvec, hs, R, part, attb, out, newh);
}

// Round 3
// 262.837 us; speedup vs baseline: 1.0298x; 1.0226x over previous
//
#include <hip/hip_runtime.h>
#include <cstddef>

// Shapes: BS=16, N=1024, HID=64, D=128, F=128, C=256, NM=4, PREK=4
constexpr float PHASE_SCALE = (float)(3.141592653589793 / ((12.0 + 2.0) / 64.0));

typedef __bf16 bf16;
typedef __bf16 bf16x4 __attribute__((ext_vector_type(4)));
typedef __bf16 bf16x8 __attribute__((ext_vector_type(8)));
typedef float floatx4 __attribute__((ext_vector_type(4)));

#define GLOAD_LDS16(gp, lp) __builtin_amdgcn_global_load_lds( \
    (const __attribute__((address_space(1))) void*)(gp),      \
    (__attribute__((address_space(3))) void*)(lp), 16, 0, 0)

#define VM_WAIT(n) asm volatile("s_waitcnt vmcnt(" #n ")" ::: "memory")

// ============ fused prep (round-0 section order; x0 build vectorized) ============
// [0,576): weight transposes ; [576,1088): att partials ;
// [1088,2112): x0 build (vectorized, conflict-free) ; [2112,10304): S fp32->bf16
__global__ __launch_bounds__(256) void prep_kernel(
    const float4* __restrict__ S, bf16* __restrict__ Sbf,
    const float* __restrict__ R,
    const float* __restrict__ gcw, const float* __restrict__ W,
    bf16* __restrict__ gtAll, bf16* __restrict__ WT,
    const float* __restrict__ inp, const float* __restrict__ hs,
    bf16* __restrict__ xRow, bf16* __restrict__ xT0,
    const float* __restrict__ attw, float* __restrict__ part)
{
    __shared__ bf16 tile[64][65];
    __shared__ float red[256];
    const int bid = blockIdx.x;
    const int tid = threadIdx.x;

    if (bid < 576) {
        // ---- weight transposes ----
        int gi = bid * 256 + tid;                 // 147,456
        if (gi < 131072) {
            int m = gi >> 15;
            int rem = gi & 32767;
            int d = rem >> 8;
            int c = rem & 255;
            gtAll[gi] = (bf16)gcw[(size_t)d * 1024 + c * 4 + m];  // gtAll[m][d][c]
        } else {
            int r = gi - 131072;
            int n = r >> 7, k = r & 127;
            WT[r] = (bf16)W[(size_t)k * 128 + n];                 // WT[n][k]
        }
    } else if (bid < 1088) {
        // ---- att partials ----
        int bid3 = bid - 576;
        int bk = bid3 & 63;                       // b*4+k
        int k = bk & 3;
        int chunk = bid3 >> 6;                    // 0..7
        const float* hbase = hs + (size_t)bk * 131072;
        float acc = 0.f;
        for (int idx = tid; idx < 2048; idx += 256) {   // 8 iters, float4
            int h4 = (idx & 15) * 4;
            int n = chunk * 128 + (idx >> 4);
            float4 rr  = *(const float4*)(R + (size_t)k * 65536 + n * 64 + h4);
            float4 re  = *(const float4*)(hbase + (size_t)n * 128 + h4);
            float4 im  = *(const float4*)(hbase + (size_t)n * 128 + 64 + h4);
            float4 wre = *(const float4*)(attw + (size_t)n * 128 + h4);
            float4 wim = *(const float4*)(attw + (size_t)n * 128 + 64 + h4);
            float sv, cv;
            __sincosf(rr.x * PHASE_SCALE, &sv, &cv);
            acc += (cv * re.x - sv * im.x) * wre.x + (sv * re.x + cv * im.x) * wim.x;
            __sincosf(rr.y * PHASE_SCALE, &sv, &cv);
            acc += (cv * re.y - sv * im.y) * wre.y + (sv * re.y + cv * im.y) * wim.y;
            __sincosf(rr.z * PHASE_SCALE, &sv, &cv);
            acc += (cv * re.z - sv * im.z) * wre.z + (sv * re.z + cv * im.z) * wim.z;
            __sincosf(rr.w * PHASE_SCALE, &sv, &cv);
            acc += (cv * re.w - sv * im.w) * wre.w + (sv * re.w + cv * im.w) * wim.w;
        }
        red[tid] = acc;
        __syncthreads();
        for (int s2 = 128; s2 > 0; s2 >>= 1) {
            if (tid < s2) red[tid] += red[tid + s2];
            __syncthreads();
        }
        if (tid == 0) part[bk * 8 + chunk] = red[0];
    } else if (bid < 2112) {
        // ---- x0 build: one 64n x 64c quarter-tile; source is block-uniform ----
        int lin = bid - 1088;
        int b = lin >> 6, by = (lin >> 2) & 15, bx = lin & 3;
        int n0 = by * 64, c0 = bx * 64;
        // c in [0,64): inp[c] ; [64,128): preH[c-64] ; [128,192): inp[64+cl] ; [192,256): preH[64+cl]
        const float* base = (bx & 1) ? (hs + (((size_t)b * 4 + 3) * 1024) * 128)
                                     : (inp + ((size_t)b * 1024) * 128);
        int soff = (bx >> 1) * 64;
        #pragma unroll
        for (int it = 0; it < 2; ++it) {
            int unit = it * 256 + tid;                  // 512 units = 64 rows x 8 segs
            int nl = unit >> 3, cs = unit & 7;
            const float* src = base + (size_t)(n0 + nl) * 128 + soff + cs * 8;
            float4 a0 = *(const float4*)src;
            float4 a1 = *(const float4*)(src + 4);
            bf16x8 o;
            o[0] = (bf16)a0.x; o[1] = (bf16)a0.y; o[2] = (bf16)a0.z; o[3] = (bf16)a0.w;
            o[4] = (bf16)a1.x; o[5] = (bf16)a1.y; o[6] = (bf16)a1.z; o[7] = (bf16)a1.w;
            *(bf16x8*)(xRow + ((size_t)b * 1024 + n0 + nl) * 256 + c0 + cs * 8) = o;
            #pragma unroll
            for (int e = 0; e < 8; ++e) tile[nl][cs * 8 + e] = o[e];
        }
        __syncthreads();
        #pragma unroll
        for (int it = 0; it < 4; ++it) {
            int unit = it * 256 + tid;                  // 1024 units = 64 cols x 16 n-groups
            int ng = unit & 15, cc = unit >> 4;
            bf16x4 v;
            #pragma unroll
            for (int r = 0; r < 4; ++r) v[r] = tile[ng * 4 + r][cc];
            *(bf16x4*)(xT0 + ((size_t)b * 256 + c0 + cc) * 1024 + n0 + ng * 4) = v;
        }
    } else {
        // ---- S fp32->bf16 streaming (1 unit/thread, 8192 independent blocks) ----
        int gi = (bid - 2112) * 256 + tid;        // 2,097,152 threads x 8 floats
        const float4* Sp = S + (size_t)gi * 2;
        float4 v0 = Sp[0];
        float4 v1 = Sp[1];
        bf16x8 o;
        o[0] = (bf16)v0.x; o[1] = (bf16)v0.y; o[2] = (bf16)v0.z; o[3] = (bf16)v0.w;
        o[4] = (bf16)v1.x; o[5] = (bf16)v1.y; o[6] = (bf16)v1.z; o[7] = (bf16)v1.w;
        *(bf16x8*)(Sbf + (size_t)gi * 8) = o;
    }
}

// ============ Chebyshev MFMA + fused per-hop gco ===========
// Block = 64 rows x 256 cols (full C) of one batch. 256 blocks, 8 waves (512 thr).
// LDS TRIPLE-buffered (3 x 40KB); depth-2 prefetch; counted vmcnt(5) at the barrier
// (T4: next buffer's DMA stays in flight across the barrier; never drain to 0 in-loop).
// Stage issue AFTER compute: buffer (i+2)%3 written at end of step i was read at
// step i-1; all waves passed barrier i => reads complete => single barrier/step is safe.
__global__ __launch_bounds__(512) void cheb_mfma_kernel(
    const bf16* __restrict__ S, const bf16* __restrict__ xT,
    const bf16* __restrict__ xTprev, bf16* __restrict__ outT,
    const bf16* __restrict__ xRow0, const bf16* __restrict__ gtA,
    const bf16* __restrict__ gt0, float* __restrict__ gcoF,
    float alpha, int accumulate)
{
    __shared__ char smem[122880];                 // 3 x (A 8KB + B 32KB)
    const int f = blockIdx.x;
    const int b = (f & 7) + 8 * ((f >> 3) & 1);   // batch -> XCD f%8
    const int n0 = (f >> 4) * 64;
    const int tid = threadIdx.x;
    const int wave = tid >> 6, lane = tid & 63;
    const int wr = (wave & 3) * 16;               // 16-row group
    const int wc = (wave >> 2) * 128;             // 128-col half
    const int l15 = lane & 15, quad = lane >> 4;
    const int lrow = lane >> 3;                   // staging: 8 rows x 8 segs
    const int segsw = (lane & 7) ^ lrow;

    const bf16* Sb = S + (size_t)b * 1048576;
    const bf16* xb = xT + (size_t)b * 262144;

    auto stage = [&](int buf, int k0) {
        bf16* dA = (bf16*)(smem + buf * 40960);
        bf16* dB = dA + 4096;                     // 8192 B after A
        // A: wave stages rows [wave*8, wave*8+8)   (1 gload_lds)
        {
            const bf16* gp = Sb + (size_t)(n0 + wave * 8 + lrow) * 1024 + k0 + segsw * 8;
            GLOAD_LDS16(gp, dA + wave * 8 * 64);
        }
        // B: wave stages cols [wave*32, wave*32+32) (4 gload_lds)
        #pragma unroll
        for (int v = 0; v < 4; ++v) {
            int cq = wave * 32 + v * 8;
            const bf16* gp = xb + (size_t)(cq + lrow) * 1024 + k0 + segsw * 8;
            GLOAD_LDS16(gp, dB + cq * 64);
        }
    };

    floatx4 acc[8] = {};
    stage(0, 0);
    stage(1, 64);
    for (int i = 0; i < 16; ++i) {
        // wait for buffer i's 5 loads; leave buffer i+1's 5 in flight (FIFO vmcnt)
        if (i < 15) { VM_WAIT(5); } else { VM_WAIT(0); }
        __builtin_amdgcn_s_barrier();             // make buffer-i completion collective
        __builtin_amdgcn_sched_barrier(0);        // no hoisting of LDS reads above barrier
        const bf16* lA = (const bf16*)(smem + (i % 3) * 40960);
        const bf16* lB = lA + 4096;
        #pragma unroll
        for (int ks = 0; ks < 2; ++ks) {
            int row = wr + l15;
            int aslot = (ks * 4 + quad) ^ (row & 7);
            bf16x8 af = *(const bf16x8*)(lA + row * 64 + aslot * 8);
            #pragma unroll
            for (int j = 0; j < 8; ++j) {
                int col = wc + j * 16 + l15;
                int bslot = (ks * 4 + quad) ^ (col & 7);
                bf16x8 bfr = *(const bf16x8*)(lB + col * 64 + bslot * 8);
                acc[j] = __builtin_amdgcn_mfma_f32_16x16x32_bf16(af, bfr, acc[j], 0, 0, 0);
            }
        }
        // prefetch 2 steps ahead into buffer (i+2)%3 (safe: read at step i-1, done)
        if (i + 2 < 16) stage((i + 2) % 3, (i + 2) * 64);
    }

    // ---- epilogue: xnext = alpha*acc - xprev ----
    const bf16* pT = xTprev ? xTprev + (size_t)b * 262144 : nullptr;
    bf16* oT = outT ? outT + (size_t)b * 262144 : nullptr;
    bf16x4 xo[8];
    #pragma unroll
    for (int j = 0; j < 8; ++j) {
        int col = wc + j * 16 + l15;
        float v[4];
        #pragma unroll
        for (int r = 0; r < 4; ++r) v[r] = alpha * acc[j][r];
        if (pT) {
            bf16x4 pp = *(const bf16x4*)(pT + (size_t)col * 1024 + n0 + wr + quad * 4);
            #pragma unroll
            for (int r = 0; r < 4; ++r) v[r] -= (float)pp[r];
        }
        #pragma unroll
        for (int r = 0; r < 4; ++r) xo[j][r] = (bf16)v[r];
        if (oT) *(bf16x4*)(oT + (size_t)col * 1024 + n0 + wr + quad * 4) = xo[j];
    }

    // ---- LDS transpose of xnext tile (64 x 256, pad to 264) ----
    __syncthreads();                              // all waves done reading buffers
    bf16* ldsX = (bf16*)smem;
    #pragma unroll
    for (int j = 0; j < 8; ++j) {
        int col = wc + j * 16 + l15;
        #pragma unroll
        for (int r = 0; r < 4; ++r)
            ldsX[(wr + quad * 4 + r) * 264 + col] = xo[j][r];
    }
    __syncthreads();

    // ---- gco: (xnext tile) @ gt_h^T (+ x0 @ gt0^T on hop1) -> gcoF rows ----
    const int dbase = (wave >> 2) * 64;           // this wave's 64 d-cols
    floatx4 a2[4] = {};
    for (int k2 = 0; k2 < 256; k2 += 32) {
        bf16x8 af = *(const bf16x8*)(ldsX + (wr + l15) * 264 + k2 + quad * 8);
        #pragma unroll
        for (int j = 0; j < 4; ++j) {
            int dcol = dbase + j * 16 + l15;
            bf16x8 bfr = *(const bf16x8*)(gtA + (size_t)dcol * 256 + k2 + quad * 8);
            a2[j] = __builtin_amdgcn_mfma_f32_16x16x32_bf16(af, bfr, a2[j], 0, 0, 0);
        }
    }
    if (xRow0) {                                  // hop1: add x0 @ gt0^T
        for (int k2 = 0; k2 < 256; k2 += 32) {
            bf16x8 af = *(const bf16x8*)(xRow0 + ((size_t)b * 1024 + n0 + wr + l15) * 256 + k2 + quad * 8);
            #pragma unroll
            for (int j = 0; j < 4; ++j) {
                int dcol = dbase + j * 16 + l15;
                bf16x8 bfr = *(const bf16x8*)(gt0 + (size_t)dcol * 256 + k2 + quad * 8);
                a2[j] = __builtin_amdgcn_mfma_f32_16x16x32_bf16(af, bfr, a2[j], 0, 0, 0);
            }
        }
    }
    #pragma unroll
    for (int j = 0; j < 4; ++j) {
        int dcol = dbase + j * 16 + l15;
        #pragma unroll
        for (int r = 0; r < 4; ++r) {
            size_t idx = ((size_t)b * 1024 + n0 + wr + quad * 4 + r) * 128 + dcol;
            if (accumulate) gcoF[idx] += a2[j][r];
            else            gcoF[idx]  = a2[j][r];
        }
    }
}

// ============ final: out = leaky(gcoF+gcb) @ WT^T + b + att ; + newh copy + newh[3] ============
// 256 blocks x 64 rows; no LDS (A-frags built in-register from gcoF).
__global__ __launch_bounds__(256) void final_kernel(
    const float* __restrict__ gcoF, const float* __restrict__ gcb,
    const bf16* __restrict__ WT, const float* __restrict__ bvec,
    const float* __restrict__ hs, const float* __restrict__ R,
    const float* __restrict__ part, const float* __restrict__ attb,
    float* __restrict__ out, float* __restrict__ newh)
{
    const int m0 = blockIdx.x * 64;
    const int b = m0 >> 10, n0 = m0 & 1023;
    const int tid = threadIdx.x;
    const int wave = tid >> 6, lane = tid & 63;
    const int l15 = lane & 15, quad = lane >> 4;

    // ---- phase A: leaky(gcoF+gcb) @ W ----
    const int arow = m0 + wave * 16 + l15;
    floatx4 acc[8] = {};
    #pragma unroll
    for (int k0 = 0; k0 < 128; k0 += 32) {
        int kk = k0 + quad * 8;
        float4 p0 = *(const float4*)(gcoF + (size_t)arow * 128 + kk);
        float4 p1 = *(const float4*)(gcoF + (size_t)arow * 128 + kk + 4);
        float4 g0 = *(const float4*)(gcb + kk);
        float4 g1 = *(const float4*)(gcb + kk + 4);
        float vv[8] = {p0.x + g0.x, p0.y + g0.y, p0.z + g0.z, p0.w + g0.w,
                       p1.x + g1.x, p1.y + g1.y, p1.z + g1.z, p1.w + g1.w};
        bf16x8 af;
        #pragma unroll
        for (int e = 0; e < 8; ++e) {
            float v = vv[e];
            af[e] = (bf16)(v >= 0.f ? v : 0.01f * v);
        }
        #pragma unroll
        for (int j = 0; j < 8; ++j) {
            bf16x8 bfr = *(const bf16x8*)(WT + (size_t)(j * 16 + l15) * 128 + kk);
            acc[j] = __builtin_amdgcn_mfma_f32_16x16x32_bf16(af, bfr, acc[j], 0, 0, 0);
        }
    }

    // ---- softmax weights wa[b][k] from partials ----
    float sa[4], mx = -1e30f;
    #pragma unroll
    for (int k = 0; k < 4; ++k) {
        float s = attb[0];
        #pragma unroll
        for (int c = 0; c < 8; ++c) s += part[(b * 4 + k) * 8 + c];
        sa[k] = s;
        mx = fmaxf(mx, s);
    }
    float den = 0.f;
    #pragma unroll
    for (int k = 0; k < 4; ++k) { sa[k] = __expf(sa[k] - mx); den += sa[k]; }
    float inv = 1.f / den;
    #pragma unroll
    for (int k = 0; k < 4; ++k) sa[k] *= inv;

    // ---- phase B: att + newh copy + stores (jj pairs d and d+64) ----
    #pragma unroll
    for (int jj = 0; jj < 4; ++jj) {
        int hcol = jj * 16 + l15;                 // h in [0,64)
        #pragma unroll
        for (int r = 0; r < 4; ++r) {
            int n = n0 + wave * 16 + quad * 4 + r;
            float attRe = 0.f, attIm = 0.f;
            #pragma unroll
            for (int k = 0; k < 4; ++k) {
                const float* hb = hs + (((size_t)(b * 4 + k) * 1024 + n) * 128);
                float re = hb[hcol], im = hb[64 + hcol];
                float s, c;
                __sincosf(R[(size_t)k * 65536 + n * 64 + hcol] * PHASE_SCALE, &s, &c);
                attRe += sa[k] * (c * re - s * im);
                attIm += sa[k] * (s * re + c * im);
                if (k >= 1) {
                    size_t nb = (size_t)b * 524288 + (size_t)(k - 1) * 131072 + (size_t)n * 128;
                    newh[nb + hcol] = re;
                    newh[nb + 64 + hcol] = im;
                }
            }
            size_t ob = (size_t)(m0 + wave * 16 + quad * 4 + r) * 128;
            float oRe = acc[jj][r]     + bvec[(size_t)n * 128 + hcol]      + attRe;
            float oIm = acc[jj + 4][r] + bvec[(size_t)n * 128 + 64 + hcol] + attIm;
            out[ob + hcol] = oRe;
            out[ob + 64 + hcol] = oIm;
            size_t nb3 = (size_t)b * 524288 + 393216 + (size_t)n * 128;
            newh[nb3 + hcol] = oRe;
            newh[nb3 + 64 + hcol] = oIm;
        }
    }
}

extern "C" void kernel_launch(void* const* d_in, const int* in_sizes, int n_in,
                              void* d_out, int out_size, void* d_ws, size_t ws_size,
                              hipStream_t stream) {
    const float* inp  = (const float*)d_in[0];
    const float* sup  = (const float*)d_in[1];
    const float* hs   = (const float*)d_in[2];
    const float* W    = (const float*)d_in[3];
    const float* bvec = (const float*)d_in[4];
    const float* R    = (const float*)d_in[5];
    const float* gcw  = (const float*)d_in[6];
    const float* gcb  = (const float*)d_in[7];
    // d_in[8], d_in[9] (ev_att_w/b) dead: softmax over size-1 axis == 1
    const float* attw = (const float*)d_in[10];
    const float* attb = (const float*)d_in[11];

    float* out  = (float*)d_out;                    // (16,1024,128)
    float* newh = out + 2097152;                    // (16,4,1024,128)
    bf16*  Sbf  = (bf16*)newh;                      // S bf16 here until final_kernel

    char* w = (char*)d_ws;
    bf16*  xT0   = (bf16*)(w);                      // 8 MB  [16][256][1024]
    bf16*  xT1   = (bf16*)(w + 8388608);            // 8 MB
    bf16*  xT2   = (bf16*)(w + 16777216);           // 8 MB
    bf16*  xRow  = (bf16*)(w + 25165824);           // 8 MB  [16384][256]
    float* gcoF  = (float*)(w + 33554432);          // 8 MB  [16384][128]
    bf16*  gtAll = (bf16*)(w + 41943040);           // 256 KB [4][128][256]
    bf16*  WT    = (bf16*)(w + 42205184);           // 32 KB  [128][128]
    float* part  = (float*)(w + 42237952);          // 2 KB
    // total ~40.3 MB

    prep_kernel<<<10304, 256, 0, stream>>>((const float4*)sup, Sbf, R, gcw, W,
                                           gtAll, WT, inp, hs, xRow, xT0, attw, part);

    // hop1: x1 = S@x0 ; gcoF = x0@g0 + x1@g1
    cheb_mfma_kernel<<<256, 512, 0, stream>>>(Sbf, xT0, nullptr, xT1,
                                              xRow, gtAll + 32768, gtAll, gcoF, 1.0f, 0);
    // hop2: x2 = 2S@x1 - x0 ; gcoF += x2@g2
    cheb_mfma_kernel<<<256, 512, 0, stream>>>(Sbf, xT1, xT0, xT2,
                                              nullptr, gtAll + 2 * 32768, nullptr, gcoF, 2.0f, 1);
    // hop3: x3 = 2S@x2 - x1 ; gcoF += x3@g3 (no xT output)
    cheb_mfma_kernel<<<256, 512, 0, stream>>>(Sbf, xT2, xT1, nullptr,
                                              nullptr, gtAll + 3 * 32768, nullptr, gcoF, 2.0f, 1);

    // Sbf (in newh region) dead now -> final writes out + all of newh
    final_kernel<<<256, 256, 0, stream>>>(gcoF, gcb, WT, bvec, hs, R, part, attb, out, newh);
}